// Round 1
// baseline (770.148 us; speedup 1.0000x reference)
//
#include <hip/hip_runtime.h>

// Weighted 2-layer GCN, N=20000 nodes, E=320000 edges, T=4, F_IN=128, HID=256, F_OUT=128.
//
// Design notes:
//  - BatchNorm (training mode) subtracts batch mean right after h = agg@W + b,
//    so the biases b0/b1 cancel EXACTLY -> never read them.
//  - Aggregation (segment_sum of ew*x[src]) is linear, so it commutes with the
//    dense GEMM. Layer 1: gather-first (128-wide). Layer 2: GEMM-first, then
//    gather 128-wide (halves gather traffic vs gathering 256-wide).
//  - CSR built per launch (count/scan/fill) -> per-node register accumulation,
//    no float atomics on the 655 MB scatter stream.
//  - BN+ReLU of layer 1 fused into layer-2 GEMM A-tile load.

#define T_DIM 4
#define F_DIM 128
#define HID   256
#define TF    512  // T_DIM * F_DIM

// ---------------- CSR build ----------------
__global__ void count_kernel(const int* __restrict__ dst, int E, int* __restrict__ deg) {
    int e = blockIdx.x * blockDim.x + threadIdx.x;
    if (e < E) atomicAdd(&deg[dst[e]], 1);
}

__global__ void scan_kernel(const int* __restrict__ deg, int* __restrict__ row_start,
                            int* __restrict__ cursor, int n) {
    __shared__ int part[1024];
    int tid = threadIdx.x;
    int chunk = (n + 1023) >> 10;
    int begin = tid * chunk;
    if (begin > n) begin = n;
    int end = begin + chunk;
    if (end > n) end = n;
    int s = 0;
    for (int i = begin; i < end; ++i) s += deg[i];
    part[tid] = s;
    __syncthreads();
    for (int off = 1; off < 1024; off <<= 1) {
        int v = (tid >= off) ? part[tid - off] : 0;
        __syncthreads();
        part[tid] += v;
        __syncthreads();
    }
    int excl = (tid == 0) ? 0 : part[tid - 1];
    for (int i = begin; i < end; ++i) {
        row_start[i] = excl;
        cursor[i] = excl;
        excl += deg[i];
    }
    if (tid == 1023) row_start[n] = part[1023];
}

__global__ void fill_kernel(const int* __restrict__ src, const int* __restrict__ dst, int E,
                            int* __restrict__ cursor, int* __restrict__ esrc,
                            int* __restrict__ eidx) {
    int e = blockIdx.x * blockDim.x + threadIdx.x;
    if (e < E) {
        int d = dst[e];
        int p = atomicAdd(&cursor[d], 1);
        esrc[p] = src[e];
        eidx[p] = e;
    }
}

// ---------------- aggregation: out[n,t,f] = sum_e ew[e,t]*x[src[e],t,f], F=128 ----------------
__global__ __launch_bounds__(256) void agg_kernel(
        const float* __restrict__ x, const float* __restrict__ ew,
        const int* __restrict__ row_start, const int* __restrict__ esrc,
        const int* __restrict__ eidx, float* __restrict__ out) {
    const int n = blockIdx.x;
    const int j = threadIdx.x;          // covers (t,f) flat index j and j+256
    const int t0 = j >> 7;              // 0 or 1 (wave-uniform)
    const int beg = row_start[n], end = row_start[n + 1];
    float acc0 = 0.f, acc1 = 0.f;
    for (int i = beg; i < end; ++i) {
        const int s = esrc[i];
        const int e = eidx[i];
        const float* xr = x + (size_t)s * TF;
        const float w0 = ew[e * T_DIM + t0];        // wave-uniform broadcast
        const float w1 = ew[e * T_DIM + t0 + 2];
        acc0 = fmaf(w0, xr[j], acc0);
        acc1 = fmaf(w1, xr[j + 256], acc1);
    }
    const size_t o = (size_t)n * TF + j;
    out[o] = acc0;
    out[o + 256] = acc1;
}

// ---------------- GEMM: out[r,c] = sum_k A[r,k]*W[k,c]; optional fused BN+ReLU on A ----------------
template<int K, int NC, int CT, bool FUSE>
__global__ __launch_bounds__(256) void gemm_kernel(
        const float* __restrict__ A, const float* __restrict__ W,
        const float* __restrict__ scale, const float* __restrict__ shift,
        float* __restrict__ out) {
    constexpr int RT  = 32;        // rows per block
    constexpr int CPT = CT / 8;    // cols per thread (8 or 4)
    constexpr int AS  = K + 4;     // padded LDS row stride (16B aligned, bank-spread)
    __shared__ float Wl[K * CT];
    __shared__ float Al[RT * AS];
    const int tid = threadIdx.x;
    const int colbase = blockIdx.x * CT;
    const long rowbase = (long)blockIdx.y * RT;

    constexpr int WT4 = K * CT / 4;
    for (int l4 = tid; l4 < WT4; l4 += 256) {
        int l = l4 * 4;
        int k = l / CT, c = l % CT;
        *(float4*)&Wl[k * CT + c] = *(const float4*)&W[(long)k * NC + colbase + c];
    }
    constexpr int AT4 = RT * K / 4;
    for (int l4 = tid; l4 < AT4; l4 += 256) {
        int l = l4 * 4;
        int r = l / K, c = l % K;
        float4 v = *(const float4*)&A[(rowbase + r) * K + c];
        if (FUSE) {
            float4 sc = *(const float4*)&scale[c];
            float4 sh = *(const float4*)&shift[c];
            v.x = fmaxf(fmaf(sc.x, v.x, sh.x), 0.f);
            v.y = fmaxf(fmaf(sc.y, v.y, sh.y), 0.f);
            v.z = fmaxf(fmaf(sc.z, v.z, sh.z), 0.f);
            v.w = fmaxf(fmaf(sc.w, v.w, sh.w), 0.f);
        }
        *(float4*)&Al[r * AS + c] = v;
    }
    __syncthreads();

    const int row = tid >> 3;   // 32 rows
    const int cg  = tid & 7;    // 8 col groups
    float acc[CPT] = {};
    const float* Ar = &Al[row * AS];
    const float* Wc = &Wl[cg * CPT];
    #pragma unroll 4
    for (int k = 0; k < K; ++k) {
        const float a = Ar[k];
        #pragma unroll
        for (int q = 0; q < CPT; ++q)
            acc[q] = fmaf(a, Wc[k * CT + q], acc[q]);
    }
    float* op = &out[(rowbase + row) * NC + colbase + cg * CPT];
    #pragma unroll
    for (int q = 0; q < CPT; q += 4)
        *(float4*)&op[q] = make_float4(acc[q], acc[q + 1], acc[q + 2], acc[q + 3]);
}

// ---------------- per-channel batch stats (sum, sumsq) ----------------
template<int C>
__global__ void stats_kernel(const float* __restrict__ h, int rows,
                             float* __restrict__ sums, float* __restrict__ sqs) {
    constexpr int RPB = 256 / C;
    const int c = threadIdx.x % C;
    const int sub = threadIdx.x / C;
    float s = 0.f, s2 = 0.f;
    for (long r = (long)blockIdx.x * RPB + sub; r < rows; r += (long)gridDim.x * RPB) {
        float v = h[r * C + c];
        s += v;
        s2 = fmaf(v, v, s2);
    }
    atomicAdd(&sums[c], s);
    atomicAdd(&sqs[c], s2);
}

__global__ void finalize_kernel(const float* __restrict__ sums, const float* __restrict__ sqs,
                                const float* __restrict__ g, const float* __restrict__ be,
                                float* __restrict__ scale, float* __restrict__ shift,
                                int C, float invR) {
    int c = threadIdx.x;
    if (c < C) {
        float mean = sums[c] * invR;
        float var = sqs[c] * invR - mean * mean;
        float a = g[c] * rsqrtf(var + 1e-5f);
        scale[c] = a;
        shift[c] = fmaf(-mean, a, be[c]);
    }
}

// ---------------- final BN+ReLU (C=128) ----------------
__global__ void bnapply_kernel(const float4* __restrict__ h4,
                               const float* __restrict__ scale, const float* __restrict__ shift,
                               float4* __restrict__ out4, int n4) {
    int i = blockIdx.x * 256 + threadIdx.x;
    if (i >= n4) return;
    float4 v = h4[i];
    int cb = (i & 31) << 2;  // row length = 128 floats = 32 float4
    float4 sc = *(const float4*)&scale[cb];
    float4 sh = *(const float4*)&shift[cb];
    v.x = fmaxf(fmaf(sc.x, v.x, sh.x), 0.f);
    v.y = fmaxf(fmaf(sc.y, v.y, sh.y), 0.f);
    v.z = fmaxf(fmaf(sc.z, v.z, sh.z), 0.f);
    v.w = fmaxf(fmaf(sc.w, v.w, sh.w), 0.f);
    out4[i] = v;
}

extern "C" void kernel_launch(void* const* d_in, const int* in_sizes, int n_in,
                              void* d_out, int out_size, void* d_ws, size_t ws_size,
                              hipStream_t stream) {
    const float* x   = (const float*)d_in[0];
    const int*   ei  = (const int*)d_in[1];
    const float* ew  = (const float*)d_in[2];
    const float* W0  = (const float*)d_in[3];
    // d_in[4] = b0, d_in[8] = b1: mathematically cancelled by BatchNorm mean-subtraction.
    const float* g0  = (const float*)d_in[5];
    const float* be0 = (const float*)d_in[6];
    const float* W1  = (const float*)d_in[7];
    const float* g1  = (const float*)d_in[9];
    const float* be1 = (const float*)d_in[10];
    float* out = (float*)d_out;

    const int N = in_sizes[0] / TF;   // 20000
    const int E = in_sizes[1] / 2;    // 320000
    const int ROWS = N * T_DIM;       // 80000

    const int* src = ei;
    const int* dst = ei + E;

    // workspace layout (~167 MB)
    float* h1   = (float*)d_ws;                          // ROWS*256
    float* bufC = h1 + (size_t)ROWS * HID;               // ROWS*128 (agg0, then y2)
    float* h2   = bufC + (size_t)ROWS * F_DIM;           // ROWS*128
    int* deg       = (int*)(h2 + (size_t)ROWS * F_DIM);  // N
    int* row_start = deg + N;                            // N+1
    int* cursor    = row_start + N + 1;                  // N
    int* esrc      = cursor + N;                         // E
    int* eidx      = esrc + E;                           // E
    float* sums0   = (float*)(eidx + E);                 // 256
    float* sqs0    = sums0 + HID;                        // 256
    float* sums1   = sqs0 + HID;                         // 128
    float* sqs1    = sums1 + F_DIM;                      // 128
    float* scale0  = sqs1 + F_DIM;                       // 256
    float* shift0  = scale0 + HID;                       // 256
    float* scale1  = shift0 + HID;                       // 128
    float* shift1  = scale1 + F_DIM;                     // 128

    hipMemsetAsync(deg, 0, N * sizeof(int), stream);
    hipMemsetAsync(sums0, 0, (2 * HID + 2 * F_DIM) * sizeof(float), stream);

    const int eb = (E + 255) / 256;
    count_kernel<<<eb, 256, 0, stream>>>(dst, E, deg);
    scan_kernel<<<1, 1024, 0, stream>>>(deg, row_start, cursor, N);
    fill_kernel<<<eb, 256, 0, stream>>>(src, dst, E, cursor, esrc, eidx);

    // Layer 1: gather-first (128-wide), then GEMM 128->256
    agg_kernel<<<N, 256, 0, stream>>>(x, ew, row_start, esrc, eidx, bufC);
    gemm_kernel<128, 256, 64, false><<<dim3(4, ROWS / 32), 256, 0, stream>>>(
        bufC, W0, nullptr, nullptr, h1);
    stats_kernel<256><<<512, 256, 0, stream>>>(h1, ROWS, sums0, sqs0);
    finalize_kernel<<<1, 256, 0, stream>>>(sums0, sqs0, g0, be0, scale0, shift0, HID,
                                           1.f / (float)ROWS);

    // Layer 2: BN+ReLU fused into GEMM A-load; GEMM-first 256->128, then gather
    gemm_kernel<256, 128, 32, true><<<dim3(4, ROWS / 32), 256, 0, stream>>>(
        h1, W1, scale0, shift0, bufC);
    agg_kernel<<<N, 256, 0, stream>>>(bufC, ew, row_start, esrc, eidx, h2);
    stats_kernel<128><<<512, 256, 0, stream>>>(h2, ROWS, sums1, sqs1);
    finalize_kernel<<<1, 128, 0, stream>>>(sums1, sqs1, g1, be1, scale1, shift1, F_DIM,
                                           1.f / (float)ROWS);
    bnapply_kernel<<<(ROWS * F_DIM / 4 + 255) / 256, 256, 0, stream>>>(
        (const float4*)h2, scale1, shift1, (float4*)out, ROWS * F_DIM / 4);
}

// Round 3
// 651.255 us; speedup vs baseline: 1.1826x; 1.1826x over previous
//
#include <hip/hip_runtime.h>

// Weighted 2-layer GCN, N=20000 nodes, E=320000 edges, T=4, F_IN=128, HID=256, F_OUT=128.
//
// Design notes:
//  - BatchNorm (training mode) subtracts batch mean right after h = agg@W + b,
//    so the biases b0/b1 cancel EXACTLY -> never read them.
//  - Aggregation commutes with the dense GEMM (both linear). Layer 1:
//    gather-first (128-wide). Layer 2: GEMM-first, then gather 128-wide.
//  - CSR built per launch -> per-node register accumulation, no float atomics.
//    Edge weights are reordered into CSR order during fill (ewr), so the agg
//    loop has no second-level indirection.
//  - GEMM: 128x128 block tile, 8x8 register tile per thread (64 FMA per
//    2xds_read_b128 + 8xds_read_b32) -> VALU-bound, 35KB LDS -> 4 blocks/CU.
//  - BN+ReLU of layer 1 fused into layer-2 GEMM A-tile load.

#define T_DIM 4
#define F_DIM 128
#define HID   256
#define TF    512  // T_DIM * F_DIM

// ---------------- CSR build ----------------
__global__ void count_kernel(const int* __restrict__ dst, int E, int* __restrict__ deg) {
    int e = blockIdx.x * blockDim.x + threadIdx.x;
    if (e < E) atomicAdd(&deg[dst[e]], 1);
}

__global__ void scan_kernel(const int* __restrict__ deg, int* __restrict__ row_start,
                            int* __restrict__ cursor, int n) {
    __shared__ int part[1024];
    int tid = threadIdx.x;
    int chunk = (n + 1023) >> 10;
    int begin = tid * chunk;
    if (begin > n) begin = n;
    int end = begin + chunk;
    if (end > n) end = n;
    int s = 0;
    for (int i = begin; i < end; ++i) s += deg[i];
    part[tid] = s;
    __syncthreads();
    for (int off = 1; off < 1024; off <<= 1) {
        int v = (tid >= off) ? part[tid - off] : 0;
        __syncthreads();
        part[tid] += v;
        __syncthreads();
    }
    int excl = (tid == 0) ? 0 : part[tid - 1];
    for (int i = begin; i < end; ++i) {
        row_start[i] = excl;
        cursor[i] = excl;
        excl += deg[i];
    }
    if (tid == 1023) row_start[n] = part[1023];
}

// fill CSR adjacency; also reorder edge weights into CSR order (float4 per edge)
__global__ void fill_kernel(const int* __restrict__ src, const int* __restrict__ dst,
                            const float4* __restrict__ ew, int E,
                            int* __restrict__ cursor, int* __restrict__ esrc,
                            float4* __restrict__ ewr) {
    int e = blockIdx.x * blockDim.x + threadIdx.x;
    if (e < E) {
        int d = dst[e];
        int p = atomicAdd(&cursor[d], 1);
        esrc[p] = src[e];
        ewr[p] = ew[e];
    }
}

// ---------------- aggregation: out[n,t,f] = sum_e ew[e,t]*x[src[e],t,f], F=128 ----------------
__global__ __launch_bounds__(256) void agg_kernel(
        const float* __restrict__ x, const float* __restrict__ ewr,
        const int* __restrict__ row_start, const int* __restrict__ esrc,
        float* __restrict__ out) {
    const int n = blockIdx.x;
    const int j = threadIdx.x;          // covers (t,f) flat index j and j+256
    const int t0 = j >> 7;              // 0 or 1 (wave-uniform)
    const int beg = row_start[n], end = row_start[n + 1];
    float acc0 = 0.f, acc1 = 0.f;
    for (int i = beg; i < end; ++i) {
        const int s = esrc[i];
        const float* xr = x + (size_t)s * TF;
        const float w0 = ewr[i * T_DIM + t0];       // wave-uniform broadcast
        const float w1 = ewr[i * T_DIM + t0 + 2];
        acc0 = fmaf(w0, xr[j], acc0);
        acc1 = fmaf(w1, xr[j + 256], acc1);
    }
    const size_t o = (size_t)n * TF + j;
    out[o] = acc0;
    out[o + 256] = acc1;
}

// ---------------- GEMM: out[r,c] = sum_k A[r,k]*W[k,c]; optional fused BN+ReLU on A ------------
// 128x128 block tile, BK=32, 256 threads, 8x8 register tile.
// Row interleave (trow + 16*i): within a wave the 4 row-groups read distinct
// LDS banks (ASTR=36 floats -> bank offset 4*trow, rows 0..3 distinct).
template<int K, int NC, bool FUSE>
__global__ __launch_bounds__(256, 4) void gemm_kernel(
        const float* __restrict__ A, const float* __restrict__ W,
        const float* __restrict__ scale, const float* __restrict__ shift,
        float* __restrict__ out) {
    constexpr int BM = 128, BN = 128, BK = 32;
    constexpr int ASTR = BK + 4;  // 36 floats = 144B, keeps rows 16B-aligned
    __shared__ float Al[BM * ASTR];   // 18.4 KB
    __shared__ float Wl[BK * BN];     // 16 KB
    const int tid = threadIdx.x;
    const long rowbase = (long)blockIdx.y * BM;
    const int colbase = blockIdx.x * BN;
    const int trow = tid >> 4;   // 0..15; thread owns rows trow + 16*i
    const int tcol = tid & 15;   // 0..15; thread owns cols tcol*8 + j

    float acc[8][8] = {};

    const int nk = K / BK;
    for (int kb = 0; kb < nk; ++kb) {
        // stage A chunk (BM x BK), optionally fused BN+ReLU (channel = k index)
        #pragma unroll
        for (int it = 0; it < 4; ++it) {
            int idx = tid + it * 256;
            int r = idx >> 3, q = idx & 7;
            float4 v = *(const float4*)&A[(rowbase + r) * K + kb * BK + q * 4];
            if (FUSE) {
                int ch = kb * BK + q * 4;
                float4 sc = *(const float4*)&scale[ch];
                float4 sh = *(const float4*)&shift[ch];
                v.x = fmaxf(fmaf(sc.x, v.x, sh.x), 0.f);
                v.y = fmaxf(fmaf(sc.y, v.y, sh.y), 0.f);
                v.z = fmaxf(fmaf(sc.z, v.z, sh.z), 0.f);
                v.w = fmaxf(fmaf(sc.w, v.w, sh.w), 0.f);
            }
            *(float4*)&Al[r * ASTR + q * 4] = v;
        }
        // stage W chunk (BK x BN)
        #pragma unroll
        for (int it = 0; it < 4; ++it) {
            int idx = tid + it * 256;
            int k = idx >> 5, c4 = idx & 31;
            *(float4*)&Wl[k * BN + c4 * 4] =
                *(const float4*)&W[(long)(kb * BK + k) * NC + colbase + c4 * 4];
        }
        __syncthreads();

        #pragma unroll
        for (int kk = 0; kk < BK; ++kk) {
            float a[8], w[8];
            #pragma unroll
            for (int i = 0; i < 8; ++i) a[i] = Al[(trow + 16 * i) * ASTR + kk];
            *(float4*)&w[0] = *(const float4*)&Wl[kk * BN + tcol * 8];
            *(float4*)&w[4] = *(const float4*)&Wl[kk * BN + tcol * 8 + 4];
            #pragma unroll
            for (int i = 0; i < 8; ++i)
                #pragma unroll
                for (int j = 0; j < 8; ++j)
                    acc[i][j] = fmaf(a[i], w[j], acc[i][j]);
        }
        __syncthreads();
    }

    #pragma unroll
    for (int i = 0; i < 8; ++i) {
        float* op = &out[(rowbase + trow + 16 * i) * NC + colbase + tcol * 8];
        *(float4*)&op[0] = make_float4(acc[i][0], acc[i][1], acc[i][2], acc[i][3]);
        *(float4*)&op[4] = make_float4(acc[i][4], acc[i][5], acc[i][6], acc[i][7]);
    }
}

// ---------------- per-channel batch stats (sum, sumsq), float4-vectorized ----------------
template<int C>
__global__ __launch_bounds__(256) void stats_kernel(
        const float* __restrict__ h, int rows,
        float* __restrict__ sums, float* __restrict__ sqs) {
    constexpr int Q = C / 4;        // float4 slots per row (64 or 32)
    constexpr int RPB = 256 / Q;    // rows walked in parallel per block (4 or 8)
    const int q = threadIdx.x & (Q - 1);
    const int sub = threadIdx.x / Q;
    float4 s = make_float4(0.f, 0.f, 0.f, 0.f);
    float4 s2 = make_float4(0.f, 0.f, 0.f, 0.f);
    for (long r = (long)blockIdx.x * RPB + sub; r < rows; r += (long)gridDim.x * RPB) {
        float4 v = *(const float4*)&h[r * C + q * 4];
        s.x += v.x; s.y += v.y; s.z += v.z; s.w += v.w;
        s2.x = fmaf(v.x, v.x, s2.x); s2.y = fmaf(v.y, v.y, s2.y);
        s2.z = fmaf(v.z, v.z, s2.z); s2.w = fmaf(v.w, v.w, s2.w);
    }
    __shared__ float4 redS[256], redQ[256];
    redS[threadIdx.x] = s;
    redQ[threadIdx.x] = s2;
    __syncthreads();
    if (sub == 0) {
        #pragma unroll
        for (int u = 1; u < RPB; ++u) {
            float4 a = redS[u * Q + q], b = redQ[u * Q + q];
            s.x += a.x; s.y += a.y; s.z += a.z; s.w += a.w;
            s2.x += b.x; s2.y += b.y; s2.z += b.z; s2.w += b.w;
        }
        atomicAdd(&sums[q * 4 + 0], s.x);
        atomicAdd(&sums[q * 4 + 1], s.y);
        atomicAdd(&sums[q * 4 + 2], s.z);
        atomicAdd(&sums[q * 4 + 3], s.w);
        atomicAdd(&sqs[q * 4 + 0], s2.x);
        atomicAdd(&sqs[q * 4 + 1], s2.y);
        atomicAdd(&sqs[q * 4 + 2], s2.z);
        atomicAdd(&sqs[q * 4 + 3], s2.w);
    }
}

__global__ void finalize_kernel(const float* __restrict__ sums, const float* __restrict__ sqs,
                                const float* __restrict__ g, const float* __restrict__ be,
                                float* __restrict__ scale, float* __restrict__ shift,
                                int C, float invR) {
    int c = threadIdx.x;
    if (c < C) {
        float mean = sums[c] * invR;
        float var = sqs[c] * invR - mean * mean;
        float a = g[c] * rsqrtf(var + 1e-5f);
        scale[c] = a;
        shift[c] = fmaf(-mean, a, be[c]);
    }
}

// ---------------- final BN+ReLU (C=128) ----------------
__global__ void bnapply_kernel(const float4* __restrict__ h4,
                               const float* __restrict__ scale, const float* __restrict__ shift,
                               float4* __restrict__ out4, int n4) {
    int i = blockIdx.x * 256 + threadIdx.x;
    if (i >= n4) return;
    float4 v = h4[i];
    int cb = (i & 31) << 2;  // row length = 128 floats = 32 float4
    float4 sc = *(const float4*)&scale[cb];
    float4 sh = *(const float4*)&shift[cb];
    v.x = fmaxf(fmaf(sc.x, v.x, sh.x), 0.f);
    v.y = fmaxf(fmaf(sc.y, v.y, sh.y), 0.f);
    v.z = fmaxf(fmaf(sc.z, v.z, sh.z), 0.f);
    v.w = fmaxf(fmaf(sc.w, v.w, sh.w), 0.f);
    out4[i] = v;
}

extern "C" void kernel_launch(void* const* d_in, const int* in_sizes, int n_in,
                              void* d_out, int out_size, void* d_ws, size_t ws_size,
                              hipStream_t stream) {
    const float* x   = (const float*)d_in[0];
    const int*   ei  = (const int*)d_in[1];
    const float* ew  = (const float*)d_in[2];
    const float* W0  = (const float*)d_in[3];
    // d_in[4] = b0, d_in[8] = b1: mathematically cancelled by BatchNorm mean-subtraction.
    const float* g0  = (const float*)d_in[5];
    const float* be0 = (const float*)d_in[6];
    const float* W1  = (const float*)d_in[7];
    const float* g1  = (const float*)d_in[9];
    const float* be1 = (const float*)d_in[10];
    float* out = (float*)d_out;

    const int N = in_sizes[0] / TF;   // 20000
    const int E = in_sizes[1] / 2;    // 320000
    const int ROWS = N * T_DIM;       // 80000

    const int* src = ei;
    const int* dst = ei + E;

    // workspace layout (~168 MB)
    float* h1   = (float*)d_ws;                          // ROWS*256
    float* bufC = h1 + (size_t)ROWS * HID;               // ROWS*128 (agg0, then y2)
    float* h2   = bufC + (size_t)ROWS * F_DIM;           // ROWS*128
    int* deg       = (int*)(h2 + (size_t)ROWS * F_DIM);  // N
    int* row_start = deg + N;                            // N+1
    int* cursor    = row_start + N + 1;                  // N (+pad to 16B)
    int* esrc      = cursor + N + 1;                     // E
    float* ewr     = (float*)(esrc + E);                 // E*4 (CSR-ordered weights)
    float* sums0   = ewr + (size_t)E * 4;                // 256
    float* sqs0    = sums0 + HID;                        // 256
    float* sums1   = sqs0 + HID;                         // 128
    float* sqs1    = sums1 + F_DIM;                      // 128
    float* scale0  = sqs1 + F_DIM;                       // 256
    float* shift0  = scale0 + HID;                       // 256
    float* scale1  = shift0 + HID;                       // 128
    float* shift1  = scale1 + F_DIM;                     // 128

    hipMemsetAsync(deg, 0, N * sizeof(int), stream);
    hipMemsetAsync(sums0, 0, (2 * HID + 2 * F_DIM) * sizeof(float), stream);

    const int eb = (E + 255) / 256;
    count_kernel<<<eb, 256, 0, stream>>>(dst, E, deg);
    scan_kernel<<<1, 1024, 0, stream>>>(deg, row_start, cursor, N);
    fill_kernel<<<eb, 256, 0, stream>>>(src, dst, (const float4*)ew, E, cursor,
                                        esrc, (float4*)ewr);

    // Layer 1: gather-first (128-wide), then GEMM 128->256
    agg_kernel<<<N, 256, 0, stream>>>(x, ewr, row_start, esrc, bufC);
    gemm_kernel<128, 256, false><<<dim3(2, ROWS / 128), 256, 0, stream>>>(
        bufC, W0, nullptr, nullptr, h1);
    stats_kernel<256><<<256, 256, 0, stream>>>(h1, ROWS, sums0, sqs0);
    finalize_kernel<<<1, 256, 0, stream>>>(sums0, sqs0, g0, be0, scale0, shift0, HID,
                                           1.f / (float)ROWS);

    // Layer 2: BN+ReLU fused into GEMM A-load; GEMM-first 256->128, then gather
    gemm_kernel<256, 128, true><<<dim3(1, ROWS / 128), 256, 0, stream>>>(
        h1, W1, scale0, shift0, bufC);
    agg_kernel<<<N, 256, 0, stream>>>(bufC, ewr, row_start, esrc, h2);
    stats_kernel<128><<<256, 256, 0, stream>>>(h2, ROWS, sums1, sqs1);
    finalize_kernel<<<1, 128, 0, stream>>>(sums1, sqs1, g1, be1, scale1, shift1, F_DIM,
                                           1.f / (float)ROWS);
    bnapply_kernel<<<(ROWS * F_DIM / 4 + 255) / 256, 256, 0, stream>>>(
        (const float4*)h2, scale1, shift1, (float4*)out, ROWS * F_DIM / 4);
}

// Round 4
// 614.190 us; speedup vs baseline: 1.2539x; 1.0603x over previous
//
#include <hip/hip_runtime.h>

// Weighted 2-layer GCN, N=20000 nodes, E=320000 edges, T=4, F_IN=128, HID=256, F_OUT=128.
//
// Design notes:
//  - BatchNorm (training mode) subtracts batch mean right after h = agg@W + b,
//    so the biases b0/b1 cancel EXACTLY -> never read them.
//  - Aggregation commutes with the dense GEMM (both linear). Layer 1:
//    gather-first (128-wide). Layer 2: GEMM-first, then gather 128-wide.
//  - CSR built per launch; edge weights reordered into CSR order (ewr).
//  - Agg: float4 gather, 4 edges in flight (tid>>6 = edge slot), LDS reduce.
//  - GEMM: BMx128 tile, 8x8 (or 4x8) register tile; A read as float4 over k
//    (conflict-free); W cols split {tcol*4, 64+tcol*4} so ds_read_b128 covers
//    16 contiguous float4 -> 2-way bank aliasing (free). Layer2 BM=64 for
//    occupancy (1250 blocks).
//  - BN+ReLU of layer 1 fused into layer-2 GEMM A-tile load.

#define T_DIM 4
#define F_DIM 128
#define HID   256
#define TF    512  // T_DIM * F_DIM

// ---------------- CSR build ----------------
__global__ void count_kernel(const int* __restrict__ dst, int E, int* __restrict__ deg) {
    int e = blockIdx.x * blockDim.x + threadIdx.x;
    if (e < E) atomicAdd(&deg[dst[e]], 1);
}

__global__ void scan_kernel(const int* __restrict__ deg, int* __restrict__ row_start,
                            int* __restrict__ cursor, int n) {
    __shared__ int part[1024];
    int tid = threadIdx.x;
    int chunk = (n + 1023) >> 10;
    int begin = tid * chunk;
    if (begin > n) begin = n;
    int end = begin + chunk;
    if (end > n) end = n;
    int s = 0;
    for (int i = begin; i < end; ++i) s += deg[i];
    part[tid] = s;
    __syncthreads();
    for (int off = 1; off < 1024; off <<= 1) {
        int v = (tid >= off) ? part[tid - off] : 0;
        __syncthreads();
        part[tid] += v;
        __syncthreads();
    }
    int excl = (tid == 0) ? 0 : part[tid - 1];
    for (int i = begin; i < end; ++i) {
        row_start[i] = excl;
        cursor[i] = excl;
        excl += deg[i];
    }
    if (tid == 1023) row_start[n] = part[1023];
}

// fill CSR adjacency; also reorder edge weights into CSR order (float4 per edge)
__global__ void fill_kernel(const int* __restrict__ src, const int* __restrict__ dst,
                            const float4* __restrict__ ew, int E,
                            int* __restrict__ cursor, int* __restrict__ esrc,
                            float4* __restrict__ ewr) {
    int e = blockIdx.x * blockDim.x + threadIdx.x;
    if (e < E) {
        int d = dst[e];
        int p = atomicAdd(&cursor[d], 1);
        esrc[p] = src[e];
        ewr[p] = ew[e];
    }
}

// ---------------- aggregation: out[n,t,f] = sum_e ew[e,t]*x[src[e],t,f] ----------------
// One block per node. 4 edges in flight: p = tid>>6 picks the edge, q = tid&63
// covers float4 slots {2q, 2q+1} of the 512-float row (t = q>>4 wave-subgroup).
__global__ __launch_bounds__(256) void agg_kernel(
        const float4* __restrict__ x4, const float* __restrict__ ewr,
        const int* __restrict__ row_start, const int* __restrict__ esrc,
        float4* __restrict__ out4) {
    const int n = blockIdx.x;
    const int tid = threadIdx.x;
    const int p = tid >> 6;          // edge slot 0..3
    const int q = tid & 63;          // float4 slot pair {2q, 2q+1}
    const int t = q >> 4;            // 0..3 (floats 8q..8q+7 lie in t-block q>>4)
    const int beg = row_start[n], end = row_start[n + 1];
    float4 accA = make_float4(0.f, 0.f, 0.f, 0.f);
    float4 accB = make_float4(0.f, 0.f, 0.f, 0.f);
    for (int i = beg; i < end; i += 4) {
        const int e = i + p;
        if (e < end) {
            const int s = esrc[e];
            const float4* xr = x4 + (size_t)s * 128;
            const float w = ewr[e * 4 + t];
            float4 va = xr[2 * q], vb = xr[2 * q + 1];
            accA.x = fmaf(w, va.x, accA.x); accA.y = fmaf(w, va.y, accA.y);
            accA.z = fmaf(w, va.z, accA.z); accA.w = fmaf(w, va.w, accA.w);
            accB.x = fmaf(w, vb.x, accB.x); accB.y = fmaf(w, vb.y, accB.y);
            accB.z = fmaf(w, vb.z, accB.z); accB.w = fmaf(w, vb.w, accB.w);
        }
    }
    __shared__ float4 red[3][128];   // 6 KB
    if (p) { red[p - 1][2 * q] = accA; red[p - 1][2 * q + 1] = accB; }
    __syncthreads();
    if (p == 0) {
        #pragma unroll
        for (int r = 0; r < 3; ++r) {
            float4 a = red[r][2 * q], b = red[r][2 * q + 1];
            accA.x += a.x; accA.y += a.y; accA.z += a.z; accA.w += a.w;
            accB.x += b.x; accB.y += b.y; accB.z += b.z; accB.w += b.w;
        }
        out4[(size_t)n * 128 + 2 * q] = accA;
        out4[(size_t)n * 128 + 2 * q + 1] = accB;
    }
}

// ---------------- GEMM: out[r,c] = sum_k A[r,k]*W[k,c]; optional fused BN+ReLU on A ------------
// BM x 128 tile, BK=32, 256 threads, (BM/16) x 8 register tile.
// A read as float4 over k (broadcast within 16-lane groups, 4 distinct bank-quads).
// W cols per thread: {tcol*4..+3, 64+tcol*4..+3} -> each b128 covers 16
// contiguous float4 slots -> 2-way bank aliasing only (free).
template<int BM, int K, int NC, bool FUSE>
__global__ __launch_bounds__(256, 4) void gemm_kernel(
        const float* __restrict__ A, const float* __restrict__ W,
        const float* __restrict__ scale, const float* __restrict__ shift,
        float* __restrict__ out) {
    constexpr int BN = 128, BK = 32;
    constexpr int RPT = BM / 16;      // rows per thread (8 or 4)
    constexpr int ASTR = BK + 4;      // 36 floats; rows stay 16B-aligned
    __shared__ float Al[BM * ASTR];
    __shared__ float Wl[BK * BN];
    const int tid = threadIdx.x;
    const long rowbase = (long)blockIdx.y * BM;
    const int colbase = blockIdx.x * BN;
    const int trow = tid >> 4;   // 0..15; rows trow + 16*i
    const int tcol = tid & 15;   // cols tcol*4..+3 and 64+tcol*4..+3

    float acc[RPT][8] = {};

    const int nk = K / BK;
    for (int kb = 0; kb < nk; ++kb) {
        // stage A chunk (BM x BK), optionally fused BN+ReLU (channel = k index)
        #pragma unroll
        for (int it = 0; it < BM * BK / 1024; ++it) {
            int idx = tid + it * 256;
            int r = idx >> 3, q = idx & 7;
            float4 v = *(const float4*)&A[(rowbase + r) * K + kb * BK + q * 4];
            if (FUSE) {
                int ch = kb * BK + q * 4;
                float4 sc = *(const float4*)&scale[ch];
                float4 sh = *(const float4*)&shift[ch];
                v.x = fmaxf(fmaf(sc.x, v.x, sh.x), 0.f);
                v.y = fmaxf(fmaf(sc.y, v.y, sh.y), 0.f);
                v.z = fmaxf(fmaf(sc.z, v.z, sh.z), 0.f);
                v.w = fmaxf(fmaf(sc.w, v.w, sh.w), 0.f);
            }
            *(float4*)&Al[r * ASTR + q * 4] = v;
        }
        // stage W chunk (BK x BN)
        #pragma unroll
        for (int it = 0; it < 4; ++it) {
            int idx = tid + it * 256;
            int k = idx >> 5, c4 = idx & 31;
            *(float4*)&Wl[k * BN + c4 * 4] =
                *(const float4*)&W[(long)(kb * BK + k) * NC + colbase + c4 * 4];
        }
        __syncthreads();

        #pragma unroll
        for (int kk4 = 0; kk4 < BK / 4; ++kk4) {
            float4 a4[RPT];
            #pragma unroll
            for (int i = 0; i < RPT; ++i)
                a4[i] = *(const float4*)&Al[(trow + 16 * i) * ASTR + kk4 * 4];
            #pragma unroll
            for (int q = 0; q < 4; ++q) {
                const int kk = kk4 * 4 + q;
                float w[8];
                *(float4*)&w[0] = *(const float4*)&Wl[kk * BN + tcol * 4];
                *(float4*)&w[4] = *(const float4*)&Wl[kk * BN + 64 + tcol * 4];
                #pragma unroll
                for (int i = 0; i < RPT; ++i) {
                    const float a = (q == 0) ? a4[i].x : (q == 1) ? a4[i].y
                                  : (q == 2) ? a4[i].z : a4[i].w;
                    #pragma unroll
                    for (int j = 0; j < 8; ++j)
                        acc[i][j] = fmaf(a, w[j], acc[i][j]);
                }
            }
        }
        __syncthreads();
    }

    #pragma unroll
    for (int i = 0; i < RPT; ++i) {
        float* op = &out[(rowbase + trow + 16 * i) * NC + colbase + tcol * 4];
        *(float4*)&op[0]  = make_float4(acc[i][0], acc[i][1], acc[i][2], acc[i][3]);
        *(float4*)&op[64] = make_float4(acc[i][4], acc[i][5], acc[i][6], acc[i][7]);
    }
}

// ---------------- per-channel batch stats (sum, sumsq), float4-vectorized ----------------
template<int C>
__global__ __launch_bounds__(256) void stats_kernel(
        const float* __restrict__ h, int rows,
        float* __restrict__ sums, float* __restrict__ sqs) {
    constexpr int Q = C / 4;        // float4 slots per row (64 or 32)
    constexpr int RPB = 256 / Q;    // rows walked in parallel per block (4 or 8)
    const int q = threadIdx.x & (Q - 1);
    const int sub = threadIdx.x / Q;
    float4 s = make_float4(0.f, 0.f, 0.f, 0.f);
    float4 s2 = make_float4(0.f, 0.f, 0.f, 0.f);
    for (long r = (long)blockIdx.x * RPB + sub; r < rows; r += (long)gridDim.x * RPB) {
        float4 v = *(const float4*)&h[r * C + q * 4];
        s.x += v.x; s.y += v.y; s.z += v.z; s.w += v.w;
        s2.x = fmaf(v.x, v.x, s2.x); s2.y = fmaf(v.y, v.y, s2.y);
        s2.z = fmaf(v.z, v.z, s2.z); s2.w = fmaf(v.w, v.w, s2.w);
    }
    __shared__ float4 redS[256], redQ[256];
    redS[threadIdx.x] = s;
    redQ[threadIdx.x] = s2;
    __syncthreads();
    if (sub == 0) {
        #pragma unroll
        for (int u = 1; u < RPB; ++u) {
            float4 a = redS[u * Q + q], b = redQ[u * Q + q];
            s.x += a.x; s.y += a.y; s.z += a.z; s.w += a.w;
            s2.x += b.x; s2.y += b.y; s2.z += b.z; s2.w += b.w;
        }
        atomicAdd(&sums[q * 4 + 0], s.x);
        atomicAdd(&sums[q * 4 + 1], s.y);
        atomicAdd(&sums[q * 4 + 2], s.z);
        atomicAdd(&sums[q * 4 + 3], s.w);
        atomicAdd(&sqs[q * 4 + 0], s2.x);
        atomicAdd(&sqs[q * 4 + 1], s2.y);
        atomicAdd(&sqs[q * 4 + 2], s2.z);
        atomicAdd(&sqs[q * 4 + 3], s2.w);
    }
}

__global__ void finalize_kernel(const float* __restrict__ sums, const float* __restrict__ sqs,
                                const float* __restrict__ g, const float* __restrict__ be,
                                float* __restrict__ scale, float* __restrict__ shift,
                                int C, float invR) {
    int c = threadIdx.x;
    if (c < C) {
        float mean = sums[c] * invR;
        float var = sqs[c] * invR - mean * mean;
        float a = g[c] * rsqrtf(var + 1e-5f);
        scale[c] = a;
        shift[c] = fmaf(-mean, a, be[c]);
    }
}

// ---------------- final BN+ReLU (C=128) ----------------
__global__ void bnapply_kernel(const float4* __restrict__ h4,
                               const float* __restrict__ scale, const float* __restrict__ shift,
                               float4* __restrict__ out4, int n4) {
    int i = blockIdx.x * 256 + threadIdx.x;
    if (i >= n4) return;
    float4 v = h4[i];
    int cb = (i & 31) << 2;  // row length = 128 floats = 32 float4
    float4 sc = *(const float4*)&scale[cb];
    float4 sh = *(const float4*)&shift[cb];
    v.x = fmaxf(fmaf(sc.x, v.x, sh.x), 0.f);
    v.y = fmaxf(fmaf(sc.y, v.y, sh.y), 0.f);
    v.z = fmaxf(fmaf(sc.z, v.z, sh.z), 0.f);
    v.w = fmaxf(fmaf(sc.w, v.w, sh.w), 0.f);
    out4[i] = v;
}

extern "C" void kernel_launch(void* const* d_in, const int* in_sizes, int n_in,
                              void* d_out, int out_size, void* d_ws, size_t ws_size,
                              hipStream_t stream) {
    const float* x   = (const float*)d_in[0];
    const int*   ei  = (const int*)d_in[1];
    const float* ew  = (const float*)d_in[2];
    const float* W0  = (const float*)d_in[3];
    // d_in[4] = b0, d_in[8] = b1: mathematically cancelled by BatchNorm mean-subtraction.
    const float* g0  = (const float*)d_in[5];
    const float* be0 = (const float*)d_in[6];
    const float* W1  = (const float*)d_in[7];
    const float* g1  = (const float*)d_in[9];
    const float* be1 = (const float*)d_in[10];
    float* out = (float*)d_out;

    const int N = in_sizes[0] / TF;   // 20000
    const int E = in_sizes[1] / 2;    // 320000
    const int ROWS = N * T_DIM;       // 80000

    const int* src = ei;
    const int* dst = ei + E;

    // workspace layout (~168 MB)
    float* h1   = (float*)d_ws;                          // ROWS*256
    float* bufC = h1 + (size_t)ROWS * HID;               // ROWS*128 (agg0, then y2)
    float* h2   = bufC + (size_t)ROWS * F_DIM;           // ROWS*128
    int* deg       = (int*)(h2 + (size_t)ROWS * F_DIM);  // N
    int* row_start = deg + N;                            // N+1
    int* cursor    = row_start + N + 1;                  // N (+pad to 16B)
    int* esrc      = cursor + N + 1;                     // E
    float* ewr     = (float*)(esrc + E);                 // E*4 (CSR-ordered weights)
    float* sums0   = ewr + (size_t)E * 4;                // 256
    float* sqs0    = sums0 + HID;                        // 256
    float* sums1   = sqs0 + HID;                         // 128
    float* sqs1    = sums1 + F_DIM;                      // 128
    float* scale0  = sqs1 + F_DIM;                       // 256
    float* shift0  = scale0 + HID;                       // 256
    float* scale1  = shift0 + HID;                       // 128
    float* shift1  = scale1 + F_DIM;                     // 128

    hipMemsetAsync(deg, 0, N * sizeof(int), stream);
    hipMemsetAsync(sums0, 0, (2 * HID + 2 * F_DIM) * sizeof(float), stream);

    const int eb = (E + 255) / 256;
    count_kernel<<<eb, 256, 0, stream>>>(dst, E, deg);
    scan_kernel<<<1, 1024, 0, stream>>>(deg, row_start, cursor, N);
    fill_kernel<<<eb, 256, 0, stream>>>(src, dst, (const float4*)ew, E, cursor,
                                        esrc, (float4*)ewr);

    // Layer 1: gather-first (128-wide), then GEMM 128->256
    agg_kernel<<<N, 256, 0, stream>>>((const float4*)x, ewr, row_start, esrc,
                                      (float4*)bufC);
    gemm_kernel<128, 128, 256, false><<<dim3(2, ROWS / 128), 256, 0, stream>>>(
        bufC, W0, nullptr, nullptr, h1);
    stats_kernel<256><<<256, 256, 0, stream>>>(h1, ROWS, sums0, sqs0);
    finalize_kernel<<<1, 256, 0, stream>>>(sums0, sqs0, g0, be0, scale0, shift0, HID,
                                           1.f / (float)ROWS);

    // Layer 2: BN+ReLU fused into GEMM A-load; GEMM-first 256->128, then gather.
    // BM=64 -> 1250 blocks for occupancy.
    gemm_kernel<64, 256, 128, true><<<dim3(1, ROWS / 64), 256, 0, stream>>>(
        h1, W1, scale0, shift0, bufC);
    agg_kernel<<<N, 256, 0, stream>>>((const float4*)bufC, ewr, row_start, esrc,
                                      (float4*)h2);
    stats_kernel<128><<<256, 256, 0, stream>>>(h2, ROWS, sums1, sqs1);
    finalize_kernel<<<1, 128, 0, stream>>>(sums1, sqs1, g1, be1, scale1, shift1, F_DIM,
                                           1.f / (float)ROWS);
    bnapply_kernel<<<(ROWS * F_DIM / 4 + 255) / 256, 256, 0, stream>>>(
        (const float4*)h2, scale1, shift1, (float4*)out, ROWS * F_DIM / 4);
}

// Round 10
// 536.502 us; speedup vs baseline: 1.4355x; 1.1448x over previous
//
#include <hip/hip_runtime.h>

// Weighted 2-layer GCN, N=20000 nodes, E=320000 edges, T=4, F_IN=128, HID=256, F_OUT=128.
//
//  - BN subtracts batch mean right after h = agg@W + b -> biases cancel, never read.
//  - Aggregation commutes with GEMM. L1: gather-first. L2: GEMM-first, gather after.
//  - GEMMs run on MFMA via split-bf16: A = Ah+Al, W = Wh+Wl (bf16 pairs);
//    D = Ah*Wh + Ah*Wl + Al*Wh (f32 accum; dropped Al*Wl ~ 2^-16 rel).
//  - LDS tiles: 64B rows (32 bf16), 4 blocks of 16B, XOR swizzle blk ^= (row&3)
//    (bijective within the row; fragment reads spread uniformly over banks).
//    Pure-copy staging via global_load_lds (pre-swizzled per-lane SOURCE, linear dest).
//  - A/B fragments both staged as k = (lane>>4)*8 + j; any mismatch vs the hw's
//    internal k-order is a consistent k-permutation of BOTH operands -> result
//    unchanged. C/D layout (verified): col = lane&15, row = (lane>>4)*4 + j.
//  - agg1 emits A1 hi/lo bf16 directly; W transposed+split once per launch.
//  - L2 GEMM stages A through VALU with fused BN+ReLU+split.

#define T_DIM 4
#define F_DIM 128
#define HID   256
#define TF    512

typedef __attribute__((ext_vector_type(8))) short bf16x8;
typedef __attribute__((ext_vector_type(4))) float f32x4;

__device__ __forceinline__ ushort f2bf(float x) {
    union { float f; unsigned u; } v; v.f = x;
    unsigned r = v.u + 0x7FFF + ((v.u >> 16) & 1);
    return (ushort)(r >> 16);
}
__device__ __forceinline__ float bf2f(ushort b) {
    union { float f; unsigned u; } v; v.u = ((unsigned)b) << 16;
    return v.f;
}
__device__ __forceinline__ void gl_lds16(const void* gsrc, void* ldst) {
    __builtin_amdgcn_global_load_lds(
        (const __attribute__((address_space(1))) unsigned*)gsrc,
        (__attribute__((address_space(3))) unsigned*)ldst, 16, 0, 0);
}

// ---------------- CSR build ----------------
__global__ void count_kernel(const int* __restrict__ dst, int E, int* __restrict__ deg) {
    int e = blockIdx.x * blockDim.x + threadIdx.x;
    if (e < E) atomicAdd(&deg[dst[e]], 1);
}

__global__ void scan_kernel(const int* __restrict__ deg, int* __restrict__ row_start,
                            int* __restrict__ cursor, int n) {
    __shared__ int part[1024];
    int tid = threadIdx.x;
    int chunk = (n + 1023) >> 10;
    int begin = tid * chunk; if (begin > n) begin = n;
    int end = begin + chunk; if (end > n) end = n;
    int s = 0;
    for (int i = begin; i < end; ++i) s += deg[i];
    part[tid] = s;
    __syncthreads();
    for (int off = 1; off < 1024; off <<= 1) {
        int v = (tid >= off) ? part[tid - off] : 0;
        __syncthreads();
        part[tid] += v;
        __syncthreads();
    }
    int excl = (tid == 0) ? 0 : part[tid - 1];
    for (int i = begin; i < end; ++i) {
        row_start[i] = excl; cursor[i] = excl; excl += deg[i];
    }
    if (tid == 1023) row_start[n] = part[1023];
}

__global__ void fill_kernel(const int* __restrict__ src, const int* __restrict__ dst,
                            const float4* __restrict__ ew, int E,
                            int* __restrict__ cursor, int* __restrict__ esrc,
                            float4* __restrict__ ewr) {
    int e = blockIdx.x * blockDim.x + threadIdx.x;
    if (e < E) {
        int d = dst[e];
        int p = atomicAdd(&cursor[d], 1);
        esrc[p] = src[e];
        ewr[p] = ew[e];
    }
}

// ---------------- W transpose + bf16 split: W[K][NC] -> Wt_hi/lo[NC][K] ----------------
__global__ void wsplit_kernel(const float* __restrict__ W, int K, int NC,
                              ushort* __restrict__ hi, ushort* __restrict__ lo) {
    int idx = blockIdx.x * 256 + threadIdx.x;
    if (idx >= K * NC) return;
    int k = idx / NC, c = idx % NC;
    float x = W[idx];
    ushort h = f2bf(x);
    hi[(size_t)c * K + k] = h;
    lo[(size_t)c * K + k] = f2bf(x - bf2f(h));
}

// ---------------- aggregation: out[n,t,f] = sum_e ew[e,t]*x[src[e],t,f] ----------------
template<bool BF16OUT>
__global__ __launch_bounds__(256) void agg_kernel(
        const float4* __restrict__ x4, const float* __restrict__ ewr,
        const int* __restrict__ row_start, const int* __restrict__ esrc,
        float4* __restrict__ out4, ushort* __restrict__ ohi, ushort* __restrict__ olo) {
    const int n = blockIdx.x;
    const int tid = threadIdx.x;
    const int p = tid >> 6;          // edge slot 0..3 (= wave index)
    const int q = tid & 63;          // float4 slot pair {2q, 2q+1}
    const int t = q >> 4;
    const int beg = row_start[n], end = row_start[n + 1];
    float4 accA = make_float4(0.f, 0.f, 0.f, 0.f);
    float4 accB = make_float4(0.f, 0.f, 0.f, 0.f);
    for (int i = beg; i < end; i += 4) {
        const int e = i + p;
        if (e < end) {
            const int s = esrc[e];
            const float4* xr = x4 + (size_t)s * 128;
            const float w = ewr[e * 4 + t];
            float4 va = xr[2 * q], vb = xr[2 * q + 1];
            accA.x = fmaf(w, va.x, accA.x); accA.y = fmaf(w, va.y, accA.y);
            accA.z = fmaf(w, va.z, accA.z); accA.w = fmaf(w, va.w, accA.w);
            accB.x = fmaf(w, vb.x, accB.x); accB.y = fmaf(w, vb.y, accB.y);
            accB.z = fmaf(w, vb.z, accB.z); accB.w = fmaf(w, vb.w, accB.w);
        }
    }
    __shared__ float4 red[3][128];
    if (p) { red[p - 1][2 * q] = accA; red[p - 1][2 * q + 1] = accB; }
    __syncthreads();
    if (p == 0) {
        #pragma unroll
        for (int r = 0; r < 3; ++r) {
            float4 a = red[r][2 * q], b = red[r][2 * q + 1];
            accA.x += a.x; accA.y += a.y; accA.z += a.z; accA.w += a.w;
            accB.x += b.x; accB.y += b.y; accB.z += b.z; accB.w += b.w;
        }
        if (BF16OUT) {
            float v[8] = {accA.x, accA.y, accA.z, accA.w, accB.x, accB.y, accB.z, accB.w};
            uint4 hw, lw;
            unsigned hu[4], lu[4];
            #pragma unroll
            for (int j = 0; j < 4; ++j) {
                ushort h0 = f2bf(v[2 * j]), h1 = f2bf(v[2 * j + 1]);
                ushort l0 = f2bf(v[2 * j] - bf2f(h0)), l1 = f2bf(v[2 * j + 1] - bf2f(h1));
                hu[j] = (unsigned)h0 | ((unsigned)h1 << 16);
                lu[j] = (unsigned)l0 | ((unsigned)l1 << 16);
            }
            hw.x = hu[0]; hw.y = hu[1]; hw.z = hu[2]; hw.w = hu[3];
            lw.x = lu[0]; lw.y = lu[1]; lw.z = lu[2]; lw.w = lu[3];
            *(uint4*)&ohi[(size_t)n * TF + q * 8] = hw;
            *(uint4*)&olo[(size_t)n * TF + q * 8] = lw;
        } else {
            out4[(size_t)n * 128 + 2 * q] = accA;
            out4[(size_t)n * 128 + 2 * q + 1] = accB;
        }
    }
}

// ---------------- MFMA GEMM (split bf16), out[r][c] f32 ----------------
// BM x 128 tile, BK=32, 4 waves. LDS rows = 64B (32 bf16), blk ^= (row&3) swizzle.
template<int BM, int K, int NC, bool FUSE>
__global__ __launch_bounds__(256, 4) void gemm_mfma(
        const ushort* __restrict__ A_hi, const ushort* __restrict__ A_lo,
        const float* __restrict__ Af32,
        const ushort* __restrict__ Wt_hi, const ushort* __restrict__ Wt_lo,
        const float* __restrict__ scale, const float* __restrict__ shift,
        float* __restrict__ out) {
    constexpr int BN = 128;
    constexpr int MT = BM / 64;               // m-tiles per wave (2 or 1)
    __shared__ __align__(16) unsigned char AsH[BM * 64], AsL[BM * 64];
    __shared__ __align__(16) unsigned char WsH[BN * 64], WsL[BN * 64];
    const int tid = threadIdx.x;
    const int w = tid >> 6, l = tid & 63;
    const long rowbase = (long)blockIdx.y * BM;
    const int colbase = blockIdx.x * BN;

    f32x4 acc[MT][8];
    #pragma unroll
    for (int mt = 0; mt < MT; ++mt)
        #pragma unroll
        for (int nt = 0; nt < 8; ++nt) acc[mt][nt] = (f32x4){0.f, 0.f, 0.f, 0.f};

    for (int kb = 0; kb < K / 32; ++kb) {
        if (kb) __syncthreads();
        // ---- stage W tile (BN x 32) hi+lo via global_load_lds, pre-swizzled source.
        // Group c covers 16 cols; lane l -> col-in-group l>>2, block b = l&3.
        // LDS dest linear (base + lane*16); global src block = b ^ (col&3).
        {
            const int b = l & 3;
            #pragma unroll
            for (int cc = 0; cc < 2; ++cc) {
                int c = 2 * w + cc;
                int cl = c * 16 + (l >> 2);
                size_t go = (size_t)(colbase + cl) * K + kb * 32 + ((b ^ (cl & 3)) << 3);
                gl_lds16(Wt_hi + go, WsH + c * 1024);
                gl_lds16(Wt_lo + go, WsL + c * 1024);
            }
        }
        // ---- stage A tile
        if (!FUSE) {
            const int b = l & 3;
            #pragma unroll
            for (int cc = 0; cc < BM / 64; ++cc) {
                int c = w * (BM / 64) + cc;
                int r = c * 16 + (l >> 2);
                size_t go = (size_t)(rowbase + r) * K + kb * 32 + ((b ^ (r & 3)) << 3);
                gl_lds16(A_hi + go, AsH + c * 1024);
                gl_lds16(A_lo + go, AsL + c * 1024);
            }
        } else {
            #pragma unroll
            for (int p = 0; p < BM * 32 / 1024; ++p) {
                int idx = p * 256 + tid;
                int r = idx >> 3, k4 = idx & 7;
                float4 v = *(const float4*)&Af32[(rowbase + r) * K + kb * 32 + k4 * 4];
                int ch = kb * 32 + k4 * 4;
                float4 sc = *(const float4*)&scale[ch];
                float4 sh = *(const float4*)&shift[ch];
                v.x = fmaxf(fmaf(sc.x, v.x, sh.x), 0.f);
                v.y = fmaxf(fmaf(sc.y, v.y, sh.y), 0.f);
                v.z = fmaxf(fmaf(sc.z, v.z, sh.z), 0.f);
                v.w = fmaxf(fmaf(sc.w, v.w, sh.w), 0.f);
                ushort h[4], lo[4];
                float vv[4] = {v.x, v.y, v.z, v.w};
                #pragma unroll
                for (int j = 0; j < 4; ++j) {
                    h[j] = f2bf(vv[j]);
                    lo[j] = f2bf(vv[j] - bf2f(h[j]));
                }
                unsigned long long hq = (unsigned long long)((unsigned)h[0] | ((unsigned)h[1] << 16))
                                      | ((unsigned long long)((unsigned)h[2] | ((unsigned)h[3] << 16)) << 32);
                unsigned long long lq = (unsigned long long)((unsigned)lo[0] | ((unsigned)lo[1] << 16))
                                      | ((unsigned long long)((unsigned)lo[2] | ((unsigned)lo[3] << 16)) << 32);
                // block holding k-halves (k4>>1) goes at blk ^ (r&3); 8B sub-half by k4&1
                int off = r * 64 + (((k4 >> 1) ^ (r & 3)) << 4) + (k4 & 1) * 8;
                *(unsigned long long*)(AsH + off) = hq;
                *(unsigned long long*)(AsL + off) = lq;
            }
        }
        __syncthreads();

        // ---- compute: k-group g = l>>4; fragment k = g*8..g*8+7 (consistent A/B)
        const int g = l >> 4;
        bf16x8 ah[MT], al[MT];
        #pragma unroll
        for (int mt = 0; mt < MT; ++mt) {
            int ar = w * 16 * MT + mt * 16 + (l & 15);
            int off = ar * 64 + ((g ^ (ar & 3)) << 4);
            ah[mt] = *(const bf16x8*)(AsH + off);
            al[mt] = *(const bf16x8*)(AsL + off);
        }
        #pragma unroll
        for (int nt = 0; nt < 8; ++nt) {
            int bc = nt * 16 + (l & 15);
            int off = bc * 64 + ((g ^ (bc & 3)) << 4);
            bf16x8 bh = *(const bf16x8*)(WsH + off);
            bf16x8 bl = *(const bf16x8*)(WsL + off);
            #pragma unroll
            for (int mt = 0; mt < MT; ++mt) {
                acc[mt][nt] = __builtin_amdgcn_mfma_f32_16x16x32_bf16(ah[mt], bh, acc[mt][nt], 0, 0, 0);
                acc[mt][nt] = __builtin_amdgcn_mfma_f32_16x16x32_bf16(ah[mt], bl, acc[mt][nt], 0, 0, 0);
                acc[mt][nt] = __builtin_amdgcn_mfma_f32_16x16x32_bf16(al[mt], bh, acc[mt][nt], 0, 0, 0);
            }
        }
    }

    // epilogue: C/D layout col = lane&15, row = (lane>>4)*4 + j
    #pragma unroll
    for (int mt = 0; mt < MT; ++mt) {
        long r0 = rowbase + w * 16 * MT + mt * 16 + (l >> 4) * 4;
        #pragma unroll
        for (int nt = 0; nt < 8; ++nt) {
            int c = colbase + nt * 16 + (l & 15);
            #pragma unroll
            for (int j = 0; j < 4; ++j)
                out[(size_t)(r0 + j) * NC + c] = acc[mt][nt][j];
        }
    }
}

// ---------------- per-channel batch stats ----------------
template<int C>
__global__ __launch_bounds__(256) void stats_kernel(
        const float* __restrict__ h, int rows,
        float* __restrict__ sums, float* __restrict__ sqs) {
    constexpr int Q = C / 4;
    constexpr int RPB = 256 / Q;
    const int q = threadIdx.x & (Q - 1);
    const int sub = threadIdx.x / Q;
    float4 s = make_float4(0.f, 0.f, 0.f, 0.f);
    float4 s2 = make_float4(0.f, 0.f, 0.f, 0.f);
    for (long r = (long)blockIdx.x * RPB + sub; r < rows; r += (long)gridDim.x * RPB) {
        float4 v = *(const float4*)&h[r * C + q * 4];
        s.x += v.x; s.y += v.y; s.z += v.z; s.w += v.w;
        s2.x = fmaf(v.x, v.x, s2.x); s2.y = fmaf(v.y, v.y, s2.y);
        s2.z = fmaf(v.z, v.z, s2.z); s2.w = fmaf(v.w, v.w, s2.w);
    }
    __shared__ float4 redS[256], redQ[256];
    redS[threadIdx.x] = s; redQ[threadIdx.x] = s2;
    __syncthreads();
    if (sub == 0) {
        #pragma unroll
        for (int u = 1; u < RPB; ++u) {
            float4 a = redS[u * Q + q], b = redQ[u * Q + q];
            s.x += a.x; s.y += a.y; s.z += a.z; s.w += a.w;
            s2.x += b.x; s2.y += b.y; s2.z += b.z; s2.w += b.w;
        }
        atomicAdd(&sums[q * 4 + 0], s.x); atomicAdd(&sums[q * 4 + 1], s.y);
        atomicAdd(&sums[q * 4 + 2], s.z); atomicAdd(&sums[q * 4 + 3], s.w);
        atomicAdd(&sqs[q * 4 + 0], s2.x); atomicAdd(&sqs[q * 4 + 1], s2.y);
        atomicAdd(&sqs[q * 4 + 2], s2.z); atomicAdd(&sqs[q * 4 + 3], s2.w);
    }
}

__global__ void finalize_kernel(const float* __restrict__ sums, const float* __restrict__ sqs,
                                const float* __restrict__ g, const float* __restrict__ be,
                                float* __restrict__ scale, float* __restrict__ shift,
                                int C, float invR) {
    int c = threadIdx.x;
    if (c < C) {
        float mean = sums[c] * invR;
        float var = sqs[c] * invR - mean * mean;
        float a = g[c] * rsqrtf(var + 1e-5f);
        scale[c] = a;
        shift[c] = fmaf(-mean, a, be[c]);
    }
}

__global__ void bnapply_kernel(const float4* __restrict__ h4,
                               const float* __restrict__ scale, const float* __restrict__ shift,
                               float4* __restrict__ out4, int n4) {
    int i = blockIdx.x * 256 + threadIdx.x;
    if (i >= n4) return;
    float4 v = h4[i];
    int cb = (i & 31) << 2;
    float4 sc = *(const float4*)&scale[cb];
    float4 sh = *(const float4*)&shift[cb];
    v.x = fmaxf(fmaf(sc.x, v.x, sh.x), 0.f);
    v.y = fmaxf(fmaf(sc.y, v.y, sh.y), 0.f);
    v.z = fmaxf(fmaf(sc.z, v.z, sh.z), 0.f);
    v.w = fmaxf(fmaf(sc.w, v.w, sh.w), 0.f);
    out4[i] = v;
}

extern "C" void kernel_launch(void* const* d_in, const int* in_sizes, int n_in,
                              void* d_out, int out_size, void* d_ws, size_t ws_size,
                              hipStream_t stream) {
    const float* x   = (const float*)d_in[0];
    const int*   ei  = (const int*)d_in[1];
    const float* ew  = (const float*)d_in[2];
    const float* W0  = (const float*)d_in[3];
    const float* g0  = (const float*)d_in[5];
    const float* be0 = (const float*)d_in[6];
    const float* W1  = (const float*)d_in[7];
    const float* g1  = (const float*)d_in[9];
    const float* be1 = (const float*)d_in[10];
    float* out = (float*)d_out;

    const int N = in_sizes[0] / TF;   // 20000
    const int E = in_sizes[1] / 2;    // 320000
    const int ROWS = N * T_DIM;       // 80000

    const int* src = ei;
    const int* dst = ei + E;

    // workspace layout (~171 MB)
    float* h1  = (float*)d_ws;                          // ROWS*256 f32
    float* y2  = h1 + (size_t)ROWS * HID;               // ROWS*128 f32
    float* h2  = y2 + (size_t)ROWS * F_DIM;             // ROWS*128 f32; aliased:
    ushort* A1h = (ushort*)h2;                          //   ROWS*128 bf16 (agg1 out)
    ushort* A1l = A1h + (size_t)ROWS * F_DIM;           //   ROWS*128 bf16
    int* deg       = (int*)(h2 + (size_t)ROWS * F_DIM); // N
    int* row_start = deg + N;                           // N+1
    int* cursor    = row_start + N + 1;                 // N (+pad)
    int* esrc      = cursor + N + 3;                    // E (16B-aligned)
    float* ewr     = (float*)(esrc + E);                // E*4
    float* sums0   = ewr + (size_t)E * 4;               // 256
    float* sqs0    = sums0 + HID;
    float* sums1   = sqs0 + HID;                        // 128
    float* sqs1    = sums1 + F_DIM;
    float* scale0  = sqs1 + F_DIM;                      // 256
    float* shift0  = scale0 + HID;
    float* scale1  = shift0 + HID;                      // 128
    float* shift1  = scale1 + F_DIM;
    ushort* Wt0h   = (ushort*)(shift1 + F_DIM);         // 256*128
    ushort* Wt0l   = Wt0h + 256 * 128;
    ushort* Wt1h   = Wt0l + 256 * 128;                  // 128*256
    ushort* Wt1l   = Wt1h + 128 * 256;

    hipMemsetAsync(deg, 0, N * sizeof(int), stream);
    hipMemsetAsync(sums0, 0, (2 * HID + 2 * F_DIM) * sizeof(float), stream);

    const int eb = (E + 255) / 256;
    count_kernel<<<eb, 256, 0, stream>>>(dst, E, deg);
    scan_kernel<<<1, 1024, 0, stream>>>(deg, row_start, cursor, N);
    fill_kernel<<<eb, 256, 0, stream>>>(src, dst, (const float4*)ew, E, cursor,
                                        esrc, (float4*)ewr);
    wsplit_kernel<<<128, 256, 0, stream>>>(W0, 128, 256, Wt0h, Wt0l);
    wsplit_kernel<<<128, 256, 0, stream>>>(W1, 256, 128, Wt1h, Wt1l);

    // Layer 1: gather-first (bf16 split out), MFMA GEMM 128->256
    agg_kernel<true><<<N, 256, 0, stream>>>((const float4*)x, ewr, row_start, esrc,
                                            nullptr, A1h, A1l);
    gemm_mfma<128, 128, 256, false><<<dim3(2, ROWS / 128), 256, 0, stream>>>(
        A1h, A1l, nullptr, Wt0h, Wt0l, nullptr, nullptr, h1);
    stats_kernel<256><<<256, 256, 0, stream>>>(h1, ROWS, sums0, sqs0);
    finalize_kernel<<<1, 256, 0, stream>>>(sums0, sqs0, g0, be0, scale0, shift0, HID,
                                           1.f / (float)ROWS);

    // Layer 2: BN+ReLU+split fused into A staging; MFMA GEMM 256->128; gather after
    gemm_mfma<64, 256, 128, true><<<dim3(1, ROWS / 64), 256, 0, stream>>>(
        nullptr, nullptr, h1, Wt1h, Wt1l, scale0, shift0, y2);
    agg_kernel<false><<<N, 256, 0, stream>>>((const float4*)y2, ewr, row_start, esrc,
                                             (float4*)h2, nullptr, nullptr);
    stats_kernel<128><<<256, 256, 0, stream>>>(h2, ROWS, sums1, sqs1);
    finalize_kernel<<<1, 128, 0, stream>>>(sums1, sqs1, g1, be1, scale1, shift1, F_DIM,
                                           1.f / (float)ROWS);
    bnapply_kernel<<<(ROWS * F_DIM / 4 + 255) / 256, 256, 0, stream>>>(
        (const float4*)h2, scale1, shift1, (float4*)out, ROWS * F_DIM / 4);
}